// Round 3
// baseline (1168.094 us; speedup 1.0000x reference)
//
#include <hip/hip_runtime.h>

typedef unsigned short u16;
typedef unsigned int u32;
typedef __bf16 bf16x8 __attribute__((ext_vector_type(8)));
typedef bf16x8 __attribute__((may_alias)) bf16x8a;   // TBAA-safe LDS loads
typedef float f32x4 __attribute__((ext_vector_type(4)));

#define BB 32
#define SS 1024
#define HH 128
#define DD 256

__device__ __forceinline__ float b2f(u16 u) {
    u32 v = ((u32)u) << 16;
    return __builtin_bit_cast(float, v);
}
__device__ __forceinline__ u16 f2b(float f) {
    u32 u = __builtin_bit_cast(u32, f);
    u32 r = (u + 0x7fffu + ((u >> 16) & 1u)) >> 16;   // RNE
    return (u16)r;
}
__device__ __forceinline__ float sig_fast(float x) {
    return __builtin_amdgcn_rcpf(1.0f + __builtin_amdgcn_exp2f(-1.4426950408889634f * x));
}
__device__ __forceinline__ float tanh_fast(float x) {
    return 2.0f * sig_fast(2.0f * x) - 1.0f;
}

// ---------------------------------------------------------------------------
// fp32 -> bf16 conversion (grid-stride, float4 / ushort4)
// ---------------------------------------------------------------------------
__global__ __launch_bounds__(256) void conv_f32_bf16(
    const float* __restrict__ src, u16* __restrict__ dst, int n4)
{
    for (int i = blockIdx.x * 256 + threadIdx.x; i < n4; i += gridDim.x * 256) {
        float4 v = ((const float4*)src)[i];
        ushort4 o;
        o.x = f2b(v.x); o.y = f2b(v.y); o.z = f2b(v.z); o.w = f2b(v.w);
        ((ushort4*)dst)[i] = o;
    }
}

// ---------------------------------------------------------------------------
// GEMM: C[M,N] = A[M,K] * Bt[N,K]^T (+ bias1 + bias2), bf16 in, fp32 acc,
// bf16 out. 128x128 tile, BK=64, 256 thr = 4 waves (2x2), wave = 64x64.
// ---------------------------------------------------------------------------
__global__ __launch_bounds__(256) void gemm_bt(
    const u16* __restrict__ A, const u16* __restrict__ Bt,
    const float* __restrict__ bias1, const float* __restrict__ bias2,
    u16* __restrict__ Cout, int K, int N)
{
    __shared__ u16 As[128 * 72];   // rows m, padded
    __shared__ u16 Bs[128 * 72];   // rows n, padded
    const int tid = threadIdx.x;
    const int lane = tid & 63, wave = tid >> 6;
    const int wm = wave >> 1, wn = wave & 1;
    const int lo = lane & 15, hi = lane >> 4;
    const int m0 = blockIdx.x * 128, n0 = blockIdx.y * 128;

    f32x4 acc[4][4] = {};

    for (int k0 = 0; k0 < K; k0 += 64) {
        __syncthreads();
#pragma unroll
        for (int i = 0; i < 4; i++) {
            int c = tid + 256 * i;
            int row = c >> 3, kc = (c & 7) * 8;
            *(uint4*)&As[row * 72 + kc] =
                *(const uint4*)&A[(size_t)(m0 + row) * K + k0 + kc];
            *(uint4*)&Bs[row * 72 + kc] =
                *(const uint4*)&Bt[(size_t)(n0 + row) * K + k0 + kc];
        }
        __syncthreads();
#pragma unroll
        for (int ks = 0; ks < 2; ks++) {
            bf16x8 af[4], bfr[4];
#pragma unroll
            for (int i = 0; i < 4; i++)
                af[i] = *(const bf16x8a*)&As[(wm * 64 + i * 16 + lo) * 72 + ks * 32 + hi * 8];
#pragma unroll
            for (int j = 0; j < 4; j++)
                bfr[j] = *(const bf16x8a*)&Bs[(wn * 64 + j * 16 + lo) * 72 + ks * 32 + hi * 8];
#pragma unroll
            for (int i = 0; i < 4; i++)
#pragma unroll
                for (int j = 0; j < 4; j++)
                    acc[i][j] = __builtin_amdgcn_mfma_f32_16x16x32_bf16(
                        af[i], bfr[j], acc[i][j], 0, 0, 0);
        }
    }
    // C layout per 16x16 tile: row = (lane>>4)*4 + reg, col = lane&15
#pragma unroll
    for (int j = 0; j < 4; j++) {
        int col = n0 + wn * 64 + j * 16 + lo;
        float bsum = 0.f;
        if (bias1 != nullptr) bsum = bias1[col] + bias2[col];
#pragma unroll
        for (int i = 0; i < 4; i++) {
            int row0 = m0 + wm * 64 + i * 16 + hi * 4;
#pragma unroll
            for (int r = 0; r < 4; r++)
                Cout[(size_t)(row0 + r) * N + col] = f2b(acc[i][j][r] + bsum);
        }
    }
}

// ---------------------------------------------------------------------------
// LSTM scan: one WG per (batch, dir). 512 threads, thread j owns gate row j:
// Whh[j][0..128] fp32 in VGPRs. h[128] broadcast via LDS each step.
// xg (bf16) = precomputed x@Wih^T + bih + bhh. 1024 sequential steps.
// ---------------------------------------------------------------------------
__global__ __launch_bounds__(512, 2) void lstm_scan(
    const float* __restrict__ fw_Whh, const float* __restrict__ bw_Whh,
    const u16* __restrict__ xg,     // [2][B*S][512] bf16
    u16* __restrict__ hout)         // [B][S][256]; fw -> [0:128], bw -> [128:256]
{
    const int wg = blockIdx.x;
    const int b = wg & 31, dir = wg >> 5;
    const int j = threadIdx.x;
    const float* Whh = dir ? bw_Whh : fw_Whh;

    float wr[128];
    {
        const float4* wp = (const float4*)(Whh + (size_t)j * 128);
#pragma unroll
        for (int i = 0; i < 32; i++) {
            float4 u = wp[i];
            wr[i * 4 + 0] = u.x; wr[i * 4 + 1] = u.y;
            wr[i * 4 + 2] = u.z; wr[i * 4 + 3] = u.w;
        }
    }

    __shared__ __align__(16) float h_lds[128];
    __shared__ float act[512];
    if (j < 128) h_lds[j] = 0.0f;
    float c = 0.0f;

    const u16* xgp = xg + ((size_t)dir * (BB * SS) + (size_t)b * SS) * 512 + j;
    u16* hop = hout + (size_t)b * SS * DD + dir * HH;
    __syncthreads();

    int s = dir ? (SS - 1) : 0;
    const int ds = dir ? -1 : 1;
    float xg_next = b2f(xgp[(size_t)s * 512]);

    for (int t = 0; t < SS; t++) {
        float xv = xg_next;
        int s_next = s + ds;
        if (t < SS - 1) xg_next = b2f(xgp[(size_t)s_next * 512]);  // prefetch

        float a0 = 0.f, a1 = 0.f, a2 = 0.f, a3 = 0.f;
        const float4* hv = (const float4*)h_lds;
#pragma unroll
        for (int i = 0; i < 32; i++) {
            float4 hh = hv[i];
            a0 = fmaf(hh.x, wr[4 * i + 0], a0);
            a1 = fmaf(hh.y, wr[4 * i + 1], a1);
            a2 = fmaf(hh.z, wr[4 * i + 2], a2);
            a3 = fmaf(hh.w, wr[4 * i + 3], a3);
        }
        float g = xv + ((a0 + a1) + (a2 + a3));
        // gate order i,f,g~,o ; wave-uniform branch (g~ = threads 256..383)
        float a = (j >= 256 && j < 384) ? tanh_fast(g) : sig_fast(g);
        act[j] = a;
        __syncthreads();
        if (j < 128) {
            float ig = act[j], fg = act[128 + j], gg = act[256 + j], og = act[384 + j];
            c = fg * c + ig * gg;
            float h = og * tanh_fast(c);
            h_lds[j] = h;
            hop[(size_t)s * DD + j] = f2b(h);
        }
        __syncthreads();
        s = s_next;
    }
}

// ---------------------------------------------------------------------------
// V transpose: v[b][s][d] -> vT[b][d][s] via LDS tiles (64x64)
// ---------------------------------------------------------------------------
__global__ __launch_bounds__(256) void transpose_v(
    const u16* __restrict__ v, u16* __restrict__ vT)
{
    __shared__ u16 tile[64 * 72];
    const int b = blockIdx.z, s0 = blockIdx.x * 64, d0 = blockIdx.y * 64;
    const int tid = threadIdx.x;
#pragma unroll
    for (int i = 0; i < 2; i++) {
        int c = tid + 256 * i;
        int sl = c >> 3, dc = (c & 7) * 8;
        *(uint4*)&tile[sl * 72 + dc] =
            *(const uint4*)&v[((size_t)b * SS + s0 + sl) * DD + d0 + dc];
    }
    __syncthreads();
#pragma unroll
    for (int i = 0; i < 2; i++) {
        int c = tid + 256 * i;
        int dl = c >> 3, sc = (c & 7) * 8;
        u32 x0 = (u32)tile[(sc + 0) * 72 + dl] | ((u32)tile[(sc + 1) * 72 + dl] << 16);
        u32 x1 = (u32)tile[(sc + 2) * 72 + dl] | ((u32)tile[(sc + 3) * 72 + dl] << 16);
        u32 x2 = (u32)tile[(sc + 4) * 72 + dl] | ((u32)tile[(sc + 5) * 72 + dl] << 16);
        u32 x3 = (u32)tile[(sc + 6) * 72 + dl] | ((u32)tile[(sc + 7) * 72 + dl] << 16);
        uint4 val; val.x = x0; val.y = x1; val.z = x2; val.w = x3;
        *(uint4*)&vT[((size_t)b * DD + d0 + dl) * SS + s0 + sc] = val;
    }
}

// ---------------------------------------------------------------------------
// Flash attention: WG = (batch, 64-row q tile), 256 thr = 4 waves, each wave
// a 16-row stripe. KV tiles of 32. exp2-domain softmax, scale folded. f32 out.
// ---------------------------------------------------------------------------
__global__ __launch_bounds__(256) void attn_kernel(
    const u16* __restrict__ q, const u16* __restrict__ k,
    const u16* __restrict__ vT, float* __restrict__ out)
{
    __shared__ u16 Ks[32 * 264];   // [s'][d], padded
    __shared__ u16 Vs[256 * 40];   // [d][s'], padded
    __shared__ u16 Ps[64 * 40];    // [q][s'], padded
    const int b = blockIdx.y, q0 = blockIdx.x * 64;
    const int tid = threadIdx.x, wave = tid >> 6, lane = tid & 63;
    const int lo = lane & 15, hi = lane >> 4;
    const float c1 = 0.09016844005556021f;  // log2(e)/16

    bf16x8 qf[8];
    {
        const u16* qp = q + ((size_t)b * SS + q0 + wave * 16 + lo) * DD;
#pragma unroll
        for (int ks = 0; ks < 8; ks++)
            qf[ks] = *(const bf16x8a*)&qp[ks * 32 + hi * 8];
    }
    float m_i[4] = {-1e30f, -1e30f, -1e30f, -1e30f};
    float l_i[4] = {0.f, 0.f, 0.f, 0.f};
    f32x4 o[16] = {};

    for (int t0 = 0; t0 < SS; t0 += 32) {
        __syncthreads();
#pragma unroll
        for (int i = 0; i < 4; i++) {
            int c = tid + 256 * i;
            {
                int row = c >> 5, dc = (c & 31) * 8;
                *(uint4*)&Ks[row * 264 + dc] =
                    *(const uint4*)&k[((size_t)b * SS + t0 + row) * DD + dc];
            }
            {
                int d = c >> 2, sc = (c & 3) * 8;
                *(uint4*)&Vs[d * 40 + sc] =
                    *(const uint4*)&vT[((size_t)b * DD + d) * SS + t0 + sc];
            }
        }
        __syncthreads();

        // S = Q K^T for this wave's 16 rows x 32 cols
        f32x4 sacc[2] = {};
#pragma unroll
        for (int ks = 0; ks < 8; ks++) {
#pragma unroll
            for (int j = 0; j < 2; j++) {
                bf16x8 bfr = *(const bf16x8a*)&Ks[(j * 16 + lo) * 264 + ks * 32 + hi * 8];
                sacc[j] = __builtin_amdgcn_mfma_f32_16x16x32_bf16(qf[ks], bfr, sacc[j], 0, 0, 0);
            }
        }

        // online softmax (exp2 domain)
        float tt[2][4];
#pragma unroll
        for (int j = 0; j < 2; j++)
#pragma unroll
            for (int r = 0; r < 4; r++) tt[j][r] = sacc[j][r] * c1;
        float rm[4];
#pragma unroll
        for (int r = 0; r < 4; r++) rm[r] = fmaxf(tt[0][r], tt[1][r]);
#pragma unroll
        for (int mm = 1; mm <= 8; mm <<= 1)
#pragma unroll
            for (int r = 0; r < 4; r++) rm[r] = fmaxf(rm[r], __shfl_xor(rm[r], mm, 64));
        float al[4], rs[4];
#pragma unroll
        for (int r = 0; r < 4; r++) {
            float mn = fmaxf(m_i[r], rm[r]);
            al[r] = __builtin_amdgcn_exp2f(m_i[r] - mn);
            m_i[r] = mn;
            rs[r] = 0.f;
        }
#pragma unroll
        for (int j = 0; j < 2; j++)
#pragma unroll
            for (int r = 0; r < 4; r++) {
                float p = __builtin_amdgcn_exp2f(tt[j][r] - m_i[r]);
                rs[r] += p;
                Ps[(wave * 16 + hi * 4 + r) * 40 + j * 16 + lo] = f2b(p);
            }
#pragma unroll
        for (int mm = 1; mm <= 8; mm <<= 1)
#pragma unroll
            for (int r = 0; r < 4; r++) rs[r] += __shfl_xor(rs[r], mm, 64);
#pragma unroll
        for (int r = 0; r < 4; r++) l_i[r] = l_i[r] * al[r] + rs[r];
#pragma unroll
        for (int nt = 0; nt < 16; nt++) {
            o[nt][0] *= al[0]; o[nt][1] *= al[1];
            o[nt][2] *= al[2]; o[nt][3] *= al[3];
        }
        // barrier orders the u16 Ps stores against the vector Ps reload
        __syncthreads();
        // O += P V  (wave reads only its own 16-row stripe of Ps)
        bf16x8 pa = *(const bf16x8a*)&Ps[(wave * 16 + lo) * 40 + hi * 8];
#pragma unroll
        for (int nt = 0; nt < 16; nt++) {
            bf16x8 bv = *(const bf16x8a*)&Vs[(nt * 16 + lo) * 40 + hi * 8];
            o[nt] = __builtin_amdgcn_mfma_f32_16x16x32_bf16(pa, bv, o[nt], 0, 0, 0);
        }
    }
    float inv[4];
#pragma unroll
    for (int r = 0; r < 4; r++) inv[r] = __builtin_amdgcn_rcpf(l_i[r]);
#pragma unroll
    for (int nt = 0; nt < 16; nt++)
#pragma unroll
        for (int r = 0; r < 4; r++) {
            int row = q0 + wave * 16 + hi * 4 + r;
            int col = nt * 16 + lo;
            out[((size_t)b * SS + row) * DD + col] = o[nt][r] * inv[r];
        }
}

// ---------------------------------------------------------------------------
extern "C" void kernel_launch(void* const* d_in, const int* in_sizes, int n_in,
                              void* d_out, int out_size, void* d_ws, size_t ws_size,
                              hipStream_t stream)
{
    (void)in_sizes; (void)n_in; (void)out_size;
    // Reference dtypes are float32 -> inputs are fp32, output is fp32.
    const float* x      = (const float*)d_in[0];
    const float* fw_Wih = (const float*)d_in[1];
    const float* fw_Whh = (const float*)d_in[2];
    const float* fw_bih = (const float*)d_in[3];
    const float* fw_bhh = (const float*)d_in[4];
    const float* bw_Wih = (const float*)d_in[5];
    const float* bw_Whh = (const float*)d_in[6];
    const float* bw_bih = (const float*)d_in[7];
    const float* bw_bhh = (const float*)d_in[8];
    const float* Wq = (const float*)d_in[9];
    const float* Wk = (const float*)d_in[10];
    const float* Wv = (const float*)d_in[11];

    // Workspace layout (total 143,261,696 B ~ 137 MiB):
    //   [0, 67108864)    xg bf16 [2][32768][512]  (dead after scan; vb aliases)
    //   +67108864        h   bf16 [32768][256]
    //   +83886080        qb  bf16
    //   +100663296       kb  bf16
    //   +117440512       vT  bf16
    //   +134217728       x16 bf16 [32768][128]
    //   +142606336       w16: fwWih, bwWih, Wq, Wk, Wv (131072 B each)
    if (ws_size < 143261696ULL) return;   // finite absmax 0.076 => ws too small

    char* ws = (char*)d_ws;
    u16* xg  = (u16*)ws;
    u16* h   = (u16*)(ws + 67108864);
    u16* qb  = (u16*)(ws + 83886080);
    u16* kb  = (u16*)(ws + 100663296);
    u16* vT  = (u16*)(ws + 117440512);
    u16* x16 = (u16*)(ws + 134217728);
    u16* wfih16 = (u16*)(ws + 142606336);
    u16* wbih16 = (u16*)(ws + 142606336 + 131072);
    u16* wq16   = (u16*)(ws + 142606336 + 262144);
    u16* wk16   = (u16*)(ws + 142606336 + 393216);
    u16* wv16   = (u16*)(ws + 142606336 + 524288);
    u16* vb = (u16*)ws;                 // aliases xg region (dead after scan)

    // fp32 -> bf16 conversions
    conv_f32_bf16<<<1024, 256, 0, stream>>>(x, x16, (BB * SS * HH) / 4);
    conv_f32_bf16<<<64, 256, 0, stream>>>(fw_Wih, wfih16, 65536 / 4);
    conv_f32_bf16<<<64, 256, 0, stream>>>(bw_Wih, wbih16, 65536 / 4);
    conv_f32_bf16<<<64, 256, 0, stream>>>(Wq, wq16, 65536 / 4);
    conv_f32_bf16<<<64, 256, 0, stream>>>(Wk, wk16, 65536 / 4);
    conv_f32_bf16<<<64, 256, 0, stream>>>(Wv, wv16, 65536 / 4);

    // xg = x @ Wih^T + bih + bhh, per direction (M=32768, N=512, K=128)
    gemm_bt<<<dim3(256, 4), 256, 0, stream>>>(x16, wfih16, fw_bih, fw_bhh, xg, 128, 512);
    gemm_bt<<<dim3(256, 4), 256, 0, stream>>>(x16, wbih16, bw_bih, bw_bhh,
                                              xg + (size_t)BB * SS * 512, 128, 512);
    // sequential bidirectional scan -> h [b][s][256]
    lstm_scan<<<64, 512, 0, stream>>>(fw_Whh, bw_Whh, xg, h);
    // q,k,v projections (M=32768, N=256, K=256)
    gemm_bt<<<dim3(256, 2), 256, 0, stream>>>(h, wq16, nullptr, nullptr, qb, 256, 256);
    gemm_bt<<<dim3(256, 2), 256, 0, stream>>>(h, wk16, nullptr, nullptr, kb, 256, 256);
    gemm_bt<<<dim3(256, 2), 256, 0, stream>>>(h, wv16, nullptr, nullptr, vb, 256, 256);
    transpose_v<<<dim3(16, 4, 32), 256, 0, stream>>>(vb, vT);
    // fused attention -> out fp32
    attn_kernel<<<dim3(16, 32), 256, 0, stream>>>(qb, kb, vT, (float*)d_out);
}